// Round 2
// baseline (252.019 us; speedup 1.0000x reference)
//
#include <hip/hip_runtime.h>
#include <hip/hip_fp16.h>
#include <hip/hip_cooperative_groups.h>

namespace cg = cooperative_groups;

// Problem constants (B=1, D=128, H=64, W=96, 4 levels, radius 4)
#define D 128
#define H0 64
#define W0 96
#define HW0 6144
#define INV_SQRT_D 0.08838834764831843f

// Half-precision feature-map workspace (offsets in _Float16 units)
#define H_F1T0 0
#define H_F1T1 786432
#define H_F1T2 983040
#define H_F1T3 1032192
#define H_F2T0 1048576
#define H_F2T1 1835008
#define H_F2T2 2031616
#define H_F2T3 2080768

// Output offsets (floats)
#define OUT_L0 0
#define OUT_L1 497664
#define OUT_L2 622080
#define OUT_L3 653184

typedef _Float16 h2 __attribute__((ext_vector_type(2)));
union F4H { float4 f; h2 h[4]; };

__device__ __forceinline__ float dot2f(h2 a, h2 b, float c) {
#if __has_builtin(__builtin_amdgcn_fdot2)
    return __builtin_amdgcn_fdot2(a, b, c, false);
#else
    return c + (float)a.x * (float)b.x + (float)a.y * (float)b.y;
#endif
}

__device__ __forceinline__ void gp_to_level(int gp, int& level, int& p) {
    if (gp < 6144)      { level = 0; p = gp; }
    else if (gp < 7680) { level = 1; p = gp - 6144; }
    else if (gp < 8064) { level = 2; p = gp - 7680; }
    else                { level = 3; p = gp - 8064; }
}

// Ternary selects instead of runtime-indexed const arrays (scratch hazard)
__device__ __forceinline__ int f1off(int l) {
    return l == 0 ? H_F1T0 : l == 1 ? H_F1T1 : l == 2 ? H_F1T2 : H_F1T3;
}
__device__ __forceinline__ int f2off(int l) {
    return l == 0 ? H_F2T0 : l == 1 ? H_F2T1 : l == 2 ? H_F2T2 : H_F2T3;
}
__device__ __forceinline__ int outoff(int l) {
    return l == 0 ? OUT_L0 : l == 1 ? OUT_L1 : l == 2 ? OUT_L2 : OUT_L3;
}

// ---------------------------------------------------------------------------
// Phase A body: tile transpose + all pool levels, fp16 outputs.
// 768 tasks (96 tiles x 2 maps x 4 d-quarters) x 512 threads.
// One float4 global load per thread (1 KiB/wave instruction).
// ---------------------------------------------------------------------------
__device__ __forceinline__ void prep_body(int b, int t,
                                          const float* __restrict__ f1,
                                          const float* __restrict__ f2,
                                          _Float16* __restrict__ wh,
                                          float* __restrict__ T) {
    const int m  = b / 384;
    const int r  = b - m * 384;
    const int tix = r >> 2;         // 0..95 tile
    const int dq  = r & 3;          // d quarter (32 channels)
    const int tr = tix / 12, tc = tix - (tix / 12) * 12;
    const float* in = (m ? f2 : f1) + dq * 32 * HW0;

    // ---- load: 32 d x 8 rows x 2 float4 = 512 slots, 1/thread
    {
        const int dl  = t >> 4;         // 0..31
        const int row = (t >> 1) & 7;   // 0..7
        const int c4  = t & 1;          // which float4 in the 8-wide row
        float4 v = *(const float4*)(in + dl * HW0 + (tr * 8 + row) * W0
                                    + tc * 8 + c4 * 4);
        const int l0 = row * 8 + c4 * 4;
        T[(l0 + 0) * 33 + dl] = v.x;
        T[(l0 + 1) * 33 + dl] = v.y;
        T[(l0 + 2) * 33 + dl] = v.z;
        T[(l0 + 3) * 33 + dl] = v.w;
    }
    __syncthreads();

    // ---- level 0: transposed fp16, vectorized h2 stores
    {
        _Float16* o0 = wh + (m ? H_F2T0 : H_F1T0) + dq * 32;
        h2* o0h = (h2*)o0;
#pragma unroll
        for (int pass = 0; pass < 2; ++pass) {
            int idx = t + pass * 512;
            int pl = idx >> 4, c2 = idx & 15;       // pixel, h2-slot
            h2 hv;
            hv.x = (_Float16)T[pl * 33 + 2 * c2];
            hv.y = (_Float16)T[pl * 33 + 2 * c2 + 1];
            int gp = (tr * 8 + (pl >> 3)) * W0 + tc * 8 + (pl & 7);
            o0h[gp * 64 + c2] = hv;
        }
    }
    // ---- level 1: 16 px x 32 d = 512, 1/thread
    {
        _Float16* o1 = wh + (m ? H_F2T1 : H_F1T1) + dq * 32;
        int d = t & 31, p1 = t >> 5;    // p1 0..15
        int i1 = p1 >> 2, j1 = p1 & 3;
        int l00 = (i1 * 2) * 8 + j1 * 2;
        float v = T[l00 * 33 + d] + T[(l00 + 1) * 33 + d]
                + T[(l00 + 8) * 33 + d] + T[(l00 + 9) * 33 + d];
        o1[((tr * 4 + i1) * 48 + tc * 4 + j1) * D + d] = (_Float16)(0.25f * v);
    }
    // ---- level 2: 4 px x 32 d = 128
    if (t < 128) {
        _Float16* o2 = wh + (m ? H_F2T2 : H_F1T2) + dq * 32;
        int d = t & 31, p2 = t >> 5;    // p2 0..3
        int i2 = p2 >> 1, j2 = p2 & 1;
        float acc = 0.0f;
#pragma unroll
        for (int a = 0; a < 4; ++a)
#pragma unroll
            for (int c2 = 0; c2 < 4; ++c2)
                acc += T[((i2 * 4 + a) * 8 + j2 * 4 + c2) * 33 + d];
        o2[((tr * 2 + i2) * 24 + tc * 2 + j2) * D + d] = (_Float16)(acc * 0.0625f);
    }
    // ---- level 3: 1 px x 32 d
    if (t < 32) {
        _Float16* o3 = wh + (m ? H_F2T3 : H_F1T3) + dq * 32;
        float acc = 0.0f;
        for (int l2 = 0; l2 < 64; ++l2) acc += T[l2 * 33 + t];
        o3[(tr * 12 + tc) * D + t] = (_Float16)(acc * 0.015625f);
    }
}

// ---------------------------------------------------------------------------
// Phase B body: one 8-pixel task (8 waves, 512 thr). Coords resize, grid
// dots (8-lane interleaved fp16 slices, 3-shfl reduce), bilinear combine.
// Tasks are level-uniform (level boundaries 6144/7680/8064 all % 8 == 0).
// ---------------------------------------------------------------------------
__device__ __forceinline__ void dc_task(int task, int t,
                                        const float* __restrict__ coords0,
                                        const _Float16* __restrict__ wh,
                                        float* __restrict__ out,
                                        float* __restrict__ Gs,
                                        float* __restrict__ cxs,
                                        float* __restrict__ cys) {
    const int w = t >> 6;               // wave = pixel-in-task (0..7)
    const int ln = t & 63;
    const int oct = ln >> 3;            // dot within iteration
    const int sub = ln & 7;             // interleaved d slice

    const int gp0 = task * 8;
    const int gp = gp0 + w;

    int level, p;
    gp_to_level(gp, level, p);
    const int Hl = H0 >> level, Wl = W0 >> level;
    const _Float16* f2t = wh + f2off(level);

    // f1 fragment hoisted first: latency hides under coords work
    const _Float16* f1p = wh + f1off(level) + p * D + sub * 8;
    F4H a0f, a1f;
    a0f.f = *(const float4*)(f1p);
    a1f.f = *(const float4*)(f1p + 64);

    // ---- coords for this wave's pixel
    float cx, cy;
    if (level == 0) {
        cx = coords0[p];
        cy = coords0[HW0 + p];
    } else {
        const int ho = p / Wl, wo = p - (p / Wl) * Wl;
        const float ff = (float)(1 << level);
        const float sfy = (ho + 0.5f) * ff - 0.5f;
        const float sfx = (wo + 0.5f) * ff - 0.5f;
        int ylo = max(0, (int)ceilf(sfy - ff));
        int yhi = min(H0 - 1, (int)floorf(sfy + ff));
        int xlo = max(0, (int)ceilf(sfx - ff));
        int xhi = min(W0 - 1, (int)floorf(sfx + ff));
        int nx = xhi - xlo + 1;
        int nt = (yhi - ylo + 1) * nx;
        float a0 = 0.0f, a1 = 0.0f, wsum = 0.0f;
        for (int i = ln; i < nt; i += 64) {
            int ry = i / nx, rx = i - ry * nx;
            int iy = ylo + ry, ix = xlo + rx;
            float wy = fmaxf(1.0f - fabsf(sfy - (float)iy) / ff, 0.0f);
            float wx = fmaxf(1.0f - fabsf(sfx - (float)ix) / ff, 0.0f);
            float wgt = wy * wx;
            wsum += wgt;
            a0 += wgt * coords0[iy * W0 + ix];
            a1 += wgt * coords0[HW0 + iy * W0 + ix];
        }
#pragma unroll
        for (int off = 32; off; off >>= 1) {
            a0 += __shfl_xor(a0, off);
            a1 += __shfl_xor(a1, off);
            wsum += __shfl_xor(wsum, off);
        }
        cx = a0 / wsum / ff;
        cy = a1 / wsum / ff;
    }
    if (ln == 0) { cxs[w] = cx; cys[w] = cy; }
    const int fx = (int)floorf(cx), fy = (int)floorf(cy);
    const int shf = 5 - level;          // Wl = 3 << shf

    // ---- grid dots
#pragma unroll 2
    for (int i = 0; i < 13; ++i) {
        int g = i * 8 + oct;
        int gc = min(g, 99);
        int gy = (gc * 205) >> 11;      // gc/10 (u24 magic)
        int gx = gc - gy * 10;
        int iy = min(max(fy - 4 + gy, 0), Hl - 1);
        int ix = min(max(fx - 4 + gx, 0), Wl - 1);
        int rowp = ((iy * 3) << shf) + ix;   // iy*Wl + ix
        const _Float16* row = f2t + rowp * D + sub * 8;
        F4H v0, v1;
        v0.f = *(const float4*)(row);
        v1.f = *(const float4*)(row + 64);
        float s = 0.0f;
        s = dot2f(a0f.h[0], v0.h[0], s);
        s = dot2f(a0f.h[1], v0.h[1], s);
        s = dot2f(a0f.h[2], v0.h[2], s);
        s = dot2f(a0f.h[3], v0.h[3], s);
        s = dot2f(a1f.h[0], v1.h[0], s);
        s = dot2f(a1f.h[1], v1.h[1], s);
        s = dot2f(a1f.h[2], v1.h[2], s);
        s = dot2f(a1f.h[3], v1.h[3], s);
        s += __shfl_xor(s, 1);
        s += __shfl_xor(s, 2);
        s += __shfl_xor(s, 4);
        if (sub == 0 && g < 100) Gs[w * 101 + g] = s;
    }
    __syncthreads();

    // ---- combine: px = t&7, k-slot = t>>3
    {
        const int px = t & 7;
        const int kk = t >> 3;          // 0..63
        int lv0, p0;
        gp_to_level(gp0, lv0, p0);
        const int Hb = H0 >> lv0, Wb = W0 >> lv0;
        const int npb = Hb * Wb;
        float* outp = out + outoff(lv0) + p0 + px;
        const float bx = cxs[px], by = cys[px];
        const float Wm1 = (float)(Wb - 1), Hm1 = (float)(Hb - 1);
        const float* Gp = &Gs[px * 101];

        for (int k = kk; k < 81; k += 64) {
            int dxi = (k * 57) >> 9;    // k/9 (u24 magic)
            int dyi = k - dxi * 9;
            float x = fminf(fmaxf(bx + (float)(dxi - 4), 0.0f), Wm1);
            float y = fminf(fmaxf(by + (float)(dyi - 4), 0.0f), Hm1);
            float wx1 = x - floorf(x), wx0 = 1.0f - wx1;
            float wy1 = y - floorf(y), wy0 = 1.0f - wy1;
            int g00 = dyi * 10 + dxi;
            float v = wx0 * wy0 * Gp[g00]      + wx1 * wy0 * Gp[g00 + 1]
                    + wx0 * wy1 * Gp[g00 + 10] + wx1 * wy1 * Gp[g00 + 11];
            outp[k * npb] = v * INV_SQRT_D;
        }
    }
}

// ---------------------------------------------------------------------------
// Fused cooperative kernel: 768 blocks x 512 thr. __launch_bounds__(512,6)
// caps VGPR at 85 -> 3 blocks/CU -> exactly 768 co-resident blocks, so the
// cooperative launch is valid by construction. LDS 11.7 KB/block.
// ---------------------------------------------------------------------------
__global__ __launch_bounds__(512, 6) void k_fused(const float* __restrict__ f1,
                                                  const float* __restrict__ f2,
                                                  const float* __restrict__ coords0,
                                                  float* __restrict__ ws,
                                                  float* __restrict__ out) {
    __shared__ float T[64 * 33];
    __shared__ float Gs[8 * 101];
    __shared__ float cxs[8], cys[8];
    _Float16* wh = (_Float16*)ws;

    prep_body(blockIdx.x, threadIdx.x, f1, f2, wh, T);

    __threadfence();                    // device-scope release of ws writes
    cg::this_grid().sync();             // replaces the kernel boundary

    for (int task = blockIdx.x; task < 1020; task += 768) {
        dc_task(task, threadIdx.x, coords0, (const _Float16*)wh, out, Gs, cxs, cys);
        __syncthreads();                // protect Gs/cxs reuse across tasks
    }
}

// ---------------------------------------------------------------------------
// Fallback (non-cooperative) path: identical math, two launches.
// ---------------------------------------------------------------------------
__global__ __launch_bounds__(512) void k_prep(const float* __restrict__ f1,
                                              const float* __restrict__ f2,
                                              float* __restrict__ ws) {
    __shared__ float T[64 * 33];
    prep_body(blockIdx.x, threadIdx.x, f1, f2, (_Float16*)ws, T);
}

__global__ __launch_bounds__(512, 6) void k_dc8(const float* __restrict__ coords0,
                                                const float* __restrict__ ws,
                                                float* __restrict__ out) {
    __shared__ float Gs[8 * 101];
    __shared__ float cxs[8], cys[8];
    dc_task(blockIdx.x, threadIdx.x, coords0, (const _Float16*)ws, out, Gs, cxs, cys);
}

// ---------------------------------------------------------------------------
extern "C" void kernel_launch(void* const* d_in, const int* in_sizes, int n_in,
                              void* d_out, int out_size, void* d_ws, size_t ws_size,
                              hipStream_t stream) {
    const float* fmap1  = (const float*)d_in[0];
    const float* fmap2  = (const float*)d_in[1];
    const float* coords = (const float*)d_in[2];
    float* out = (float*)d_out;
    float* ws = (float*)d_ws;

    void* args[] = { (void*)&fmap1, (void*)&fmap2, (void*)&coords,
                     (void*)&ws, (void*)&out };
    hipError_t err = hipLaunchCooperativeKernel(k_fused, dim3(768), dim3(512),
                                                args, 0, stream);
    if (err != hipSuccess) {
        // Non-cooperative fallback: same math, two dependent launches.
        k_prep<<<dim3(768), dim3(512), 0, stream>>>(fmap1, fmap2, ws);
        k_dc8<<<dim3(1020), dim3(512), 0, stream>>>(coords, ws, out);
    }
}

// Round 3
// 100.821 us; speedup vs baseline: 2.4997x; 2.4997x over previous
//
#include <hip/hip_runtime.h>
#include <hip/hip_fp16.h>

// Problem constants (B=1, D=128, H=64, W=96, 4 levels, radius 4)
#define D 128
#define H0 64
#define W0 96
#define HW0 6144
#define INV_SQRT_D 0.08838834764831843f

// Half-precision feature-map workspace (offsets in _Float16 units)
#define H_F1T0 0
#define H_F1T1 786432
#define H_F1T2 983040
#define H_F1T3 1032192
#define H_F2T0 1048576
#define H_F2T1 1835008
#define H_F2T2 2031616
#define H_F2T3 2080768

// Output offsets (floats)
#define OUT_L0 0
#define OUT_L1 497664
#define OUT_L2 622080
#define OUT_L3 653184

#define NBLOCKS 256

typedef _Float16 h2 __attribute__((ext_vector_type(2)));
union F4H { float4 f; h2 h[4]; };
union H2U { h2 h; unsigned u; };

__device__ __forceinline__ float dot2f(h2 a, h2 b, float c) {
#if __has_builtin(__builtin_amdgcn_fdot2)
    return __builtin_amdgcn_fdot2(a, b, c, false);
#else
    return c + (float)a.x * (float)b.x + (float)a.y * (float)b.y;
#endif
}

__device__ __forceinline__ void gp_to_level(int gp, int& level, int& p) {
    if (gp < 6144)      { level = 0; p = gp; }
    else if (gp < 7680) { level = 1; p = gp - 6144; }
    else if (gp < 8064) { level = 2; p = gp - 7680; }
    else                { level = 3; p = gp - 8064; }
}

__device__ __forceinline__ int f1off(int l) {
    return l == 0 ? H_F1T0 : l == 1 ? H_F1T1 : l == 2 ? H_F1T2 : H_F1T3;
}
__device__ __forceinline__ int f2off(int l) {
    return l == 0 ? H_F2T0 : l == 1 ? H_F2T1 : l == 2 ? H_F2T2 : H_F2T3;
}
__device__ __forceinline__ int outoff(int l) {
    return l == 0 ? OUT_L0 : l == 1 ? OUT_L1 : l == 2 ? OUT_L2 : OUT_L3;
}

// Agent-scope (cross-XCD visible) 4-byte store: write-through past L2, so
// the mid-kernel barrier needs no mass L2 writeback.
__device__ __forceinline__ void st_wt(unsigned* p, unsigned v) {
    __hip_atomic_store(p, v, __ATOMIC_RELAXED, __HIP_MEMORY_SCOPE_AGENT);
}

// ---------------------------------------------------------------------------
// Phase B body: one 8-pixel task on 512 threads (8 waves). Identical math to
// the verified round-1 k_dc. t in [0,512).
// ---------------------------------------------------------------------------
__device__ __forceinline__ void dc_task(int task, int t,
                                        const float* __restrict__ coords0,
                                        const _Float16* __restrict__ wh,
                                        float* __restrict__ out,
                                        float* __restrict__ Gs,
                                        float* __restrict__ cxs,
                                        float* __restrict__ cys) {
    const bool valid = task < 1020;
    task = valid ? task : 1019;

    const int w = t >> 6;               // wave = pixel-in-task (0..7)
    const int ln = t & 63;
    const int oct = ln >> 3;
    const int sub = ln & 7;

    const int gp0 = task * 8;
    const int gp = gp0 + w;

    int level, p;
    gp_to_level(gp, level, p);
    const int Hl = H0 >> level, Wl = W0 >> level;
    const _Float16* f2t = wh + f2off(level);

    // f1 fragment hoisted: latency hides under coords work
    const _Float16* f1p = wh + f1off(level) + p * D + sub * 8;
    F4H a0f, a1f;
    a0f.f = *(const float4*)(f1p);
    a1f.f = *(const float4*)(f1p + 64);

    // ---- coords for this wave's pixel
    float cx, cy;
    if (level == 0) {
        cx = coords0[p];
        cy = coords0[HW0 + p];
    } else {
        const int ho = p / Wl, wo = p - (p / Wl) * Wl;
        const float ff = (float)(1 << level);
        const float sfy = (ho + 0.5f) * ff - 0.5f;
        const float sfx = (wo + 0.5f) * ff - 0.5f;
        int ylo = max(0, (int)ceilf(sfy - ff));
        int yhi = min(H0 - 1, (int)floorf(sfy + ff));
        int xlo = max(0, (int)ceilf(sfx - ff));
        int xhi = min(W0 - 1, (int)floorf(sfx + ff));
        int nx = xhi - xlo + 1;
        int nt = (yhi - ylo + 1) * nx;
        float a0 = 0.0f, a1 = 0.0f, wsum = 0.0f;
        for (int i = ln; i < nt; i += 64) {
            int ry = i / nx, rx = i - ry * nx;
            int iy = ylo + ry, ix = xlo + rx;
            float wy = fmaxf(1.0f - fabsf(sfy - (float)iy) / ff, 0.0f);
            float wx = fmaxf(1.0f - fabsf(sfx - (float)ix) / ff, 0.0f);
            float wgt = wy * wx;
            wsum += wgt;
            a0 += wgt * coords0[iy * W0 + ix];
            a1 += wgt * coords0[HW0 + iy * W0 + ix];
        }
#pragma unroll
        for (int off = 32; off; off >>= 1) {
            a0 += __shfl_xor(a0, off);
            a1 += __shfl_xor(a1, off);
            wsum += __shfl_xor(wsum, off);
        }
        cx = a0 / wsum / ff;
        cy = a1 / wsum / ff;
    }
    if (ln == 0) { cxs[w] = cx; cys[w] = cy; }
    const int fx = (int)floorf(cx), fy = (int)floorf(cy);
    const int shf = 5 - level;          // Wl = 3 << shf

    // ---- grid dots
#pragma unroll 2
    for (int i = 0; i < 13; ++i) {
        int g = i * 8 + oct;
        int gc = min(g, 99);
        int gy = (gc * 205) >> 11;      // gc/10 (u24 magic)
        int gx = gc - gy * 10;
        int iy = min(max(fy - 4 + gy, 0), Hl - 1);
        int ix = min(max(fx - 4 + gx, 0), Wl - 1);
        int rowp = ((iy * 3) << shf) + ix;   // iy*Wl + ix
        const _Float16* row = f2t + rowp * D + sub * 8;
        F4H v0, v1;
        v0.f = *(const float4*)(row);
        v1.f = *(const float4*)(row + 64);
        float s = 0.0f;
        s = dot2f(a0f.h[0], v0.h[0], s);
        s = dot2f(a0f.h[1], v0.h[1], s);
        s = dot2f(a0f.h[2], v0.h[2], s);
        s = dot2f(a0f.h[3], v0.h[3], s);
        s = dot2f(a1f.h[0], v1.h[0], s);
        s = dot2f(a1f.h[1], v1.h[1], s);
        s = dot2f(a1f.h[2], v1.h[2], s);
        s = dot2f(a1f.h[3], v1.h[3], s);
        s += __shfl_xor(s, 1);
        s += __shfl_xor(s, 2);
        s += __shfl_xor(s, 4);
        if (sub == 0 && g < 100) Gs[w * 101 + g] = s;
    }
    __syncthreads();

    // ---- combine: px = t&7, k-slot = t>>3
    {
        const int px = t & 7;
        const int kk = t >> 3;          // 0..63
        int lv0, p0;
        gp_to_level(gp0, lv0, p0);
        const int Hb = H0 >> lv0, Wb = W0 >> lv0;
        const int npb = Hb * Wb;
        float* outp = out + outoff(lv0) + p0 + px;
        const float bx = cxs[px], by = cys[px];
        const float Wm1 = (float)(Wb - 1), Hm1 = (float)(Hb - 1);
        const float* Gp = &Gs[px * 101];

        for (int k = kk; k < 81; k += 64) {
            int dxi = (k * 57) >> 9;    // k/9 (u24 magic)
            int dyi = k - dxi * 9;
            float x = fminf(fmaxf(bx + (float)(dxi - 4), 0.0f), Wm1);
            float y = fminf(fmaxf(by + (float)(dyi - 4), 0.0f), Hm1);
            float wx1 = x - floorf(x), wx0 = 1.0f - wx1;
            float wy1 = y - floorf(y), wy0 = 1.0f - wy1;
            int g00 = dyi * 10 + dxi;
            float v = wx0 * wy0 * Gp[g00]      + wx1 * wy0 * Gp[g00 + 1]
                    + wx0 * wy1 * Gp[g00 + 10] + wx1 * wy1 * Gp[g00 + 11];
            if (valid) outp[k * npb] = v * INV_SQRT_D;
        }
    }
}

// ---------------------------------------------------------------------------
// Single fused kernel, plain (graph-capturable) launch.
// 256 blocks x 1024 thr (16 waves, 34 KB LDS): every CU can hold >=1 block,
// grid <= 256 CUs => all blocks co-resident by capacity => manual barrier is
// deadlock-free unconditionally.
// Phase A (blocks 0..191): one (map,tile) each, full 128 d. Agent-scope
// write-through stores -> no cross-XCD dirty-L2 state.
// Barrier: ONE release fence + atomic arrive + spin + ONE acquire fence per
// block (256 fences total -- round 2's mistake was 393K of them).
// Phase B: 1020 tasks, 2 per block-half x 2 rounds.
// ---------------------------------------------------------------------------
__global__ __launch_bounds__(1024) void k_all(const float* __restrict__ f1,
                                              const float* __restrict__ f2,
                                              const float* __restrict__ coords0,
                                              float* __restrict__ ws,
                                              float* __restrict__ out,
                                              unsigned* __restrict__ ctr) {
    __shared__ float T[64 * 133];       // phase A: [px][d] pad 133; phase B: reused
    const int t = threadIdx.x;
    const int bid = blockIdx.x;
    _Float16* wh = (_Float16*)ws;

    // ================= Phase A =================
    if (bid < 192) {
        const int m = bid >= 96;
        const int tix = m ? bid - 96 : bid;
        const int tr = tix / 12, tc = tix - (tix / 12) * 12;
        const float* in = m ? f2 : f1;

        // load: 128 d x 64 px = 2048 float4, 2 per thread
#pragma unroll
        for (int pass = 0; pass < 2; ++pass) {
            int idx = t + pass * 1024;
            int dl = idx >> 4, slot = idx & 15;
            int row = slot >> 1, c4 = slot & 1;
            float4 v = *(const float4*)(in + dl * HW0 + (tr * 8 + row) * W0
                                        + tc * 8 + c4 * 4);
            int px = row * 8 + c4 * 4;
            T[(px + 0) * 133 + dl] = v.x;
            T[(px + 1) * 133 + dl] = v.y;
            T[(px + 2) * 133 + dl] = v.z;
            T[(px + 3) * 133 + dl] = v.w;
        }
        __syncthreads();

        // level 0: 64 px x 64 d-pairs = 4096, 4/thread
        {
            unsigned* o0 = (unsigned*)(wh + (m ? H_F2T0 : H_F1T0));
#pragma unroll
            for (int pass = 0; pass < 4; ++pass) {
                int idx = t + pass * 1024;
                int pl = idx >> 6, c2 = idx & 63;
                H2U u;
                u.h.x = (_Float16)T[pl * 133 + 2 * c2];
                u.h.y = (_Float16)T[pl * 133 + 2 * c2 + 1];
                int gp = (tr * 8 + (pl >> 3)) * W0 + tc * 8 + (pl & 7);
                st_wt(o0 + gp * 64 + c2, u.u);
            }
        }
        // level 1: 16 px x 64 d-pairs = 1024, 1/thread
        {
            unsigned* o1 = (unsigned*)(wh + (m ? H_F2T1 : H_F1T1));
            int c2 = t & 63, p1 = t >> 6;
            int i1 = p1 >> 2, j1 = p1 & 3;
            int l00 = (i1 * 2) * 8 + j1 * 2;
            int d0 = 2 * c2;
            float s0 = T[l00 * 133 + d0]     + T[(l00 + 1) * 133 + d0]
                     + T[(l00 + 8) * 133 + d0] + T[(l00 + 9) * 133 + d0];
            float s1 = T[l00 * 133 + d0 + 1]     + T[(l00 + 1) * 133 + d0 + 1]
                     + T[(l00 + 8) * 133 + d0 + 1] + T[(l00 + 9) * 133 + d0 + 1];
            H2U u;
            u.h.x = (_Float16)(0.25f * s0);
            u.h.y = (_Float16)(0.25f * s1);
            st_wt(o1 + ((tr * 4 + i1) * 48 + tc * 4 + j1) * 64 + c2, u.u);
        }
        // level 2: 4 px x 64 d-pairs = 256
        if (t < 256) {
            unsigned* o2 = (unsigned*)(wh + (m ? H_F2T2 : H_F1T2));
            int c2 = t & 63, p2 = t >> 6;
            int i2 = p2 >> 1, j2 = p2 & 1;
            int d0 = 2 * c2;
            float s0 = 0.0f, s1 = 0.0f;
#pragma unroll
            for (int a = 0; a < 4; ++a)
#pragma unroll
                for (int c = 0; c < 4; ++c) {
                    int px = (i2 * 4 + a) * 8 + j2 * 4 + c;
                    s0 += T[px * 133 + d0];
                    s1 += T[px * 133 + d0 + 1];
                }
            H2U u;
            u.h.x = (_Float16)(s0 * 0.0625f);
            u.h.y = (_Float16)(s1 * 0.0625f);
            st_wt(o2 + ((tr * 2 + i2) * 24 + tc * 2 + j2) * 64 + c2, u.u);
        }
        // level 3: 64 d-pairs
        if (t < 64) {
            unsigned* o3 = (unsigned*)(wh + (m ? H_F2T3 : H_F1T3));
            int d0 = 2 * t;
            float s0 = 0.0f, s1 = 0.0f;
            for (int px = 0; px < 64; ++px) {
                s0 += T[px * 133 + d0];
                s1 += T[px * 133 + d0 + 1];
            }
            H2U u;
            u.h.x = (_Float16)(s0 * 0.015625f);
            u.h.y = (_Float16)(s1 * 0.015625f);
            st_wt(o3 + (tr * 12 + tc) * 64 + t, u.u);
        }
    }

    // ================= Grid barrier (manual, capacity-safe) =================
    __syncthreads();                    // drains this block's stores (vmcnt)
    if (t == 0) {
        __threadfence();                // release: flush any dirty L2 lines
        __hip_atomic_fetch_add(ctr, 1u, __ATOMIC_RELEASE,
                               __HIP_MEMORY_SCOPE_AGENT);
        while (__hip_atomic_load(ctr, __ATOMIC_RELAXED,
                                 __HIP_MEMORY_SCOPE_AGENT) < NBLOCKS)
            __builtin_amdgcn_s_sleep(1);
        __threadfence();                // acquire: invalidate stale L1/L2
    }
    __syncthreads();

    // ================= Phase B =================
    const int h = t >> 9;               // block half (0/1), 8 waves each
    const int t5 = t & 511;
    float* Gs  = T + h * 808;
    float* cxs = T + 1616 + h * 8;
    float* cys = T + 1632 + h * 8;

#pragma unroll 1
    for (int r = 0; r < 2; ++r) {
        int task = r * 512 + bid * 2 + h;   // covers 0..1023 (>=1020 masked)
        dc_task(task, t5, coords0, (const _Float16*)wh, out, Gs, cxs, cys);
        __syncthreads();                // protect Gs/cxs reuse across rounds
    }
}

// ---------------------------------------------------------------------------
extern "C" void kernel_launch(void* const* d_in, const int* in_sizes, int n_in,
                              void* d_out, int out_size, void* d_ws, size_t ws_size,
                              hipStream_t stream) {
    const float* fmap1  = (const float*)d_in[0];
    const float* fmap2  = (const float*)d_in[1];
    const float* coords = (const float*)d_in[2];
    float* out = (float*)d_out;
    float* ws = (float*)d_ws;

    // barrier counter: last 256-aligned word of ws (poisoned every iteration
    // by the harness -> must re-zero via a stream op, which is graph-safe)
    size_t off = (ws_size - 256) & ~(size_t)255;
    unsigned* ctr = (unsigned*)((char*)d_ws + off);
    hipMemsetAsync(ctr, 0, sizeof(unsigned), stream);

    k_all<<<dim3(NBLOCKS), dim3(1024), 0, stream>>>(fmap1, fmap2, coords,
                                                    ws, out, ctr);
}

// Round 4
// 78.441 us; speedup vs baseline: 3.2129x; 1.2853x over previous
//
#include <hip/hip_runtime.h>
#include <hip/hip_fp16.h>

// Problem constants (B=1, D=128, H=64, W=96, 4 levels, radius 4)
#define D 128
#define H0 64
#define W0 96
#define HW0 6144
#define INV_SQRT_D 0.08838834764831843f

// Half-precision feature-map workspace (offsets in _Float16 units)
#define H_F1T0 0
#define H_F1T1 786432
#define H_F1T2 983040
#define H_F1T3 1032192
#define H_F2T0 1048576
#define H_F2T1 1835008
#define H_F2T2 2031616
#define H_F2T3 2080768

// Output offsets (floats)
#define OUT_L0 0
#define OUT_L1 497664
#define OUT_L2 622080
#define OUT_L3 653184

typedef _Float16 h2 __attribute__((ext_vector_type(2)));
union F4H { float4 f; h2 h[4]; };

__device__ __forceinline__ float dot2f(h2 a, h2 b, float c) {
#if __has_builtin(__builtin_amdgcn_fdot2)
    return __builtin_amdgcn_fdot2(a, b, c, false);
#else
    return c + (float)a.x * (float)b.x + (float)a.y * (float)b.y;
#endif
}

__device__ __forceinline__ void gp_to_level(int gp, int& level, int& p) {
    if (gp < 6144)      { level = 0; p = gp; }
    else if (gp < 7680) { level = 1; p = gp - 6144; }
    else if (gp < 8064) { level = 2; p = gp - 7680; }
    else                { level = 3; p = gp - 8064; }
}

__device__ __forceinline__ int f1off(int l) {
    return l == 0 ? H_F1T0 : l == 1 ? H_F1T1 : l == 2 ? H_F1T2 : H_F1T3;
}
__device__ __forceinline__ int f2off(int l) {
    return l == 0 ? H_F2T0 : l == 1 ? H_F2T1 : l == 2 ? H_F2T2 : H_F2T3;
}
__device__ __forceinline__ int outoff(int l) {
    return l == 0 ? OUT_L0 : l == 1 ? OUT_L1 : l == 2 ? OUT_L2 : OUT_L3;
}

// ---------------------------------------------------------------------------
// K1 (round-1 verified): tile transpose + all pool levels, fp16 outputs.
// 768 blocks (96 tiles x 2 maps x 4 d-quarters) x 512 threads = 24 waves/CU.
// One float4 global load per thread (1 KiB/wave instruction).
// ---------------------------------------------------------------------------
__global__ __launch_bounds__(512) void k_prep(const float* __restrict__ f1,
                                              const float* __restrict__ f2,
                                              float* __restrict__ ws) {
    const int b = blockIdx.x;
    const int t = threadIdx.x;
    _Float16* wh = (_Float16*)ws;
    __shared__ float T[64 * 33];    // [pixel_local][d_local], stride 33
    const int m  = b / 384;
    const int r  = b - m * 384;
    const int tix = r >> 2;         // 0..95 tile
    const int dq  = r & 3;          // d quarter (32 channels)
    const int tr = tix / 12, tc = tix - (tix / 12) * 12;
    const float* in = (m ? f2 : f1) + dq * 32 * HW0;

    // ---- load: 32 d x 8 rows x 2 float4 = 512 slots, 1/thread
    {
        const int dl  = t >> 4;         // 0..31
        const int row = (t >> 1) & 7;   // 0..7
        const int c4  = t & 1;
        float4 v = *(const float4*)(in + dl * HW0 + (tr * 8 + row) * W0
                                    + tc * 8 + c4 * 4);
        const int l0 = row * 8 + c4 * 4;
        T[(l0 + 0) * 33 + dl] = v.x;
        T[(l0 + 1) * 33 + dl] = v.y;
        T[(l0 + 2) * 33 + dl] = v.z;
        T[(l0 + 3) * 33 + dl] = v.w;
    }
    __syncthreads();

    // ---- level 0: transposed fp16, vectorized h2 stores
    {
        _Float16* o0 = wh + (m ? H_F2T0 : H_F1T0) + dq * 32;
        h2* o0h = (h2*)o0;
#pragma unroll
        for (int pass = 0; pass < 2; ++pass) {
            int idx = t + pass * 512;
            int pl = idx >> 4, c2 = idx & 15;
            h2 hv;
            hv.x = (_Float16)T[pl * 33 + 2 * c2];
            hv.y = (_Float16)T[pl * 33 + 2 * c2 + 1];
            int gp = (tr * 8 + (pl >> 3)) * W0 + tc * 8 + (pl & 7);
            o0h[gp * 64 + c2] = hv;
        }
    }
    // ---- level 1: 16 px x 32 d = 512, 1/thread
    {
        _Float16* o1 = wh + (m ? H_F2T1 : H_F1T1) + dq * 32;
        int d = t & 31, p1 = t >> 5;
        int i1 = p1 >> 2, j1 = p1 & 3;
        int l00 = (i1 * 2) * 8 + j1 * 2;
        float v = T[l00 * 33 + d] + T[(l00 + 1) * 33 + d]
                + T[(l00 + 8) * 33 + d] + T[(l00 + 9) * 33 + d];
        o1[((tr * 4 + i1) * 48 + tc * 4 + j1) * D + d] = (_Float16)(0.25f * v);
    }
    // ---- level 2: 4 px x 32 d = 128
    if (t < 128) {
        _Float16* o2 = wh + (m ? H_F2T2 : H_F1T2) + dq * 32;
        int d = t & 31, p2 = t >> 5;
        int i2 = p2 >> 1, j2 = p2 & 1;
        float acc = 0.0f;
#pragma unroll
        for (int a = 0; a < 4; ++a)
#pragma unroll
            for (int c2 = 0; c2 < 4; ++c2)
                acc += T[((i2 * 4 + a) * 8 + j2 * 4 + c2) * 33 + d];
        o2[((tr * 2 + i2) * 24 + tc * 2 + j2) * D + d] = (_Float16)(acc * 0.0625f);
    }
    // ---- level 3: 1 px x 32 d
    if (t < 32) {
        _Float16* o3 = wh + (m ? H_F2T3 : H_F1T3) + dq * 32;
        float acc = 0.0f;
        for (int l2 = 0; l2 < 64; ++l2) acc += T[l2 * 33 + t];
        o3[(tr * 12 + tc) * D + t] = (_Float16)(acc * 0.015625f);
    }
}

// ---------------------------------------------------------------------------
// K2: 4 pixels per 256-thread block (4 waves, 1 wave/pixel). The 13x2
// independent float4 gathers per wave are FULLY HOISTED: all 26 loads issue
// back-to-back before any consumption (~104 data VGPRs in flight), turning
// the previously ~2-deep memory pipeline into a 26-deep one.
// __launch_bounds__(256,3): VGPR cap ~168 (no spill), 3 blocks/CU =
// 12 waves/CU => ~312 outstanding gathers per CU.
// Level boundaries 6144/7680/8064 are %4==0 -> blocks stay level-uniform.
// ---------------------------------------------------------------------------
__global__ __launch_bounds__(256, 3) void k_dc4(const float* __restrict__ coords0,
                                                const float* __restrict__ ws,
                                                float* __restrict__ out) {
    __shared__ float Gs[4 * 101];
    __shared__ float cxs[4], cys[4];
    const _Float16* wh = (const _Float16*)ws;

    const int t = threadIdx.x;
    const int w = t >> 6;               // wave = pixel-in-block (0..3)
    const int ln = t & 63;
    const int oct = ln >> 3;            // dot slot within iteration
    const int sub = ln & 7;             // interleaved d slice

    const int gp0 = blockIdx.x * 4;
    const int gp = gp0 + w;

    int level, p;
    gp_to_level(gp, level, p);
    const int Hl = H0 >> level, Wl = W0 >> level;

    // f1 fragment first: latency hides under coords work
    const _Float16* f1p = wh + f1off(level) + p * D + sub * 8;
    F4H a0f, a1f;
    a0f.f = *(const float4*)(f1p);
    a1f.f = *(const float4*)(f1p + 64);

    // ---- coords for this wave's pixel
    float cx, cy;
    if (level == 0) {
        cx = coords0[p];
        cy = coords0[HW0 + p];
    } else {
        const int ho = p / Wl, wo = p - (p / Wl) * Wl;
        const float ff = (float)(1 << level);
        const float sfy = (ho + 0.5f) * ff - 0.5f;
        const float sfx = (wo + 0.5f) * ff - 0.5f;
        int ylo = max(0, (int)ceilf(sfy - ff));
        int yhi = min(H0 - 1, (int)floorf(sfy + ff));
        int xlo = max(0, (int)ceilf(sfx - ff));
        int xhi = min(W0 - 1, (int)floorf(sfx + ff));
        int nx = xhi - xlo + 1;
        int nt = (yhi - ylo + 1) * nx;
        float a0 = 0.0f, a1 = 0.0f, wsum = 0.0f;
        for (int i = ln; i < nt; i += 64) {
            int ry = i / nx, rx = i - ry * nx;
            int iy = ylo + ry, ix = xlo + rx;
            float wy = fmaxf(1.0f - fabsf(sfy - (float)iy) / ff, 0.0f);
            float wx = fmaxf(1.0f - fabsf(sfx - (float)ix) / ff, 0.0f);
            float wgt = wy * wx;
            wsum += wgt;
            a0 += wgt * coords0[iy * W0 + ix];
            a1 += wgt * coords0[HW0 + iy * W0 + ix];
        }
#pragma unroll
        for (int off = 32; off; off >>= 1) {
            a0 += __shfl_xor(a0, off);
            a1 += __shfl_xor(a1, off);
            wsum += __shfl_xor(wsum, off);
        }
        cx = a0 / wsum / ff;
        cy = a1 / wsum / ff;
    }
    if (ln == 0) { cxs[w] = cx; cys[w] = cy; }
    const int fx = (int)floorf(cx), fy = (int)floorf(cy);
    const int shf = 5 - level;          // Wl = 3 << shf

    // ---- all 13 row offsets (fp16-element units), statically indexed
    const _Float16* base = wh + f2off(level) + sub * 8;
    int off16[13];
#pragma unroll
    for (int i = 0; i < 13; ++i) {
        int g = i * 8 + oct;
        int gc = min(g, 99);
        int gy = (gc * 205) >> 11;      // gc/10 (u24 magic)
        int gx = gc - gy * 10;
        int iy = min(max(fy - 4 + gy, 0), Hl - 1);
        int ix = min(max(fx - 4 + gx, 0), Wl - 1);
        off16[i] = ((((iy * 3) << shf) + ix) << 7);   // (iy*Wl+ix)*D
    }

    // ---- issue ALL 26 gathers before consuming any
    F4H v0[13], v1[13];
#pragma unroll
    for (int i = 0; i < 13; ++i) {
        v0[i].f = *(const float4*)(base + off16[i]);
        v1[i].f = *(const float4*)(base + off16[i] + 64);
    }

    // ---- consume: 8 dot2f + 3-shfl reduce per iteration
#pragma unroll
    for (int i = 0; i < 13; ++i) {
        float s = 0.0f;
        s = dot2f(a0f.h[0], v0[i].h[0], s);
        s = dot2f(a0f.h[1], v0[i].h[1], s);
        s = dot2f(a0f.h[2], v0[i].h[2], s);
        s = dot2f(a0f.h[3], v0[i].h[3], s);
        s = dot2f(a1f.h[0], v1[i].h[0], s);
        s = dot2f(a1f.h[1], v1[i].h[1], s);
        s = dot2f(a1f.h[2], v1[i].h[2], s);
        s = dot2f(a1f.h[3], v1[i].h[3], s);
        s += __shfl_xor(s, 1);
        s += __shfl_xor(s, 2);
        s += __shfl_xor(s, 4);
        int g = i * 8 + oct;
        if (sub == 0 && g < 100) Gs[w * 101 + g] = s;
    }
    __syncthreads();

    // ---- combine: px = t&3, k-slot = t>>2 (block is level-uniform)
    {
        const int px = t & 3;
        const int kk = t >> 2;          // 0..63
        int lv0, p0;
        gp_to_level(gp0, lv0, p0);
        const int Hb = H0 >> lv0, Wb = W0 >> lv0;
        const int npb = Hb * Wb;
        float* outp = out + outoff(lv0) + p0 + px;
        const float bx = cxs[px], by = cys[px];
        const float Wm1 = (float)(Wb - 1), Hm1 = (float)(Hb - 1);
        const float* Gp = &Gs[px * 101];

        for (int k = kk; k < 81; k += 64) {
            int dxi = (k * 57) >> 9;    // k/9 (u24 magic)
            int dyi = k - dxi * 9;
            float x = fminf(fmaxf(bx + (float)(dxi - 4), 0.0f), Wm1);
            float y = fminf(fmaxf(by + (float)(dyi - 4), 0.0f), Hm1);
            float wx1 = x - floorf(x), wx0 = 1.0f - wx1;
            float wy1 = y - floorf(y), wy0 = 1.0f - wy1;
            int g00 = dyi * 10 + dxi;
            float v = wx0 * wy0 * Gp[g00]      + wx1 * wy0 * Gp[g00 + 1]
                    + wx0 * wy1 * Gp[g00 + 10] + wx1 * wy1 * Gp[g00 + 11];
            outp[k * npb] = v * INV_SQRT_D;
        }
    }
}

// ---------------------------------------------------------------------------
extern "C" void kernel_launch(void* const* d_in, const int* in_sizes, int n_in,
                              void* d_out, int out_size, void* d_ws, size_t ws_size,
                              hipStream_t stream) {
    const float* fmap1  = (const float*)d_in[0];
    const float* fmap2  = (const float*)d_in[1];
    const float* coords = (const float*)d_in[2];
    float* out = (float*)d_out;
    float* ws = (float*)d_ws;

    k_prep<<<dim3(768), dim3(512), 0, stream>>>(fmap1, fmap2, ws);
    k_dc4<<<dim3(2040), dim3(256), 0, stream>>>(coords, ws, out);
}